// Round 1
// baseline (299.239 us; speedup 1.0000x reference)
//
#include <hip/hip_runtime.h>
#include <cstddef>

// Problem constants (from reference)
#define HWDIM 32
#define NB 4
#define NC 3
#define NIMG 32
#define P_TOTAL (NIMG * HWDIM * HWDIM)   // 32768 keys
#define Q_TOTAL (NB * HWDIM * HWDIM)     // 4096 queries
#define KSTR 32                          // key row stride (floats): 27 vals + bias + 3 centers + pad
#define NSPLIT 64                        // key splits
#define KPS (P_TOTAL / NSPLIT)           // 512 keys per split
#define CHUNK 8                          // keys per max-amortization chunk

#if defined(__has_builtin) && __has_builtin(__builtin_amdgcn_exp2f)
__device__ __forceinline__ float fexp2(float x) { return __builtin_amdgcn_exp2f(x); }
#else
__device__ __forceinline__ float fexp2(float x) { return exp2f(x); }
#endif

// Kernel 1: build scaled key matrix in workspace.
// keys[p][0..26]  = patch(p) * (2*mu/(2*sigma^2)) * log2(e)        (dot-ready, exp2 domain)
// keys[p][27]     = -mu^2 * ||patch||^2 / (2*sigma^2) * log2(e)    (per-key bias)
// keys[p][28..30] = center pixel per channel
__global__ __launch_bounds__(256) void build_keys_k(
    const float* __restrict__ images, const float* __restrict__ mu_sched,
    const float* __restrict__ sigma_sched, const int* __restrict__ tptr,
    float* __restrict__ keys)
{
    int p = blockIdx.x * 256 + threadIdx.x;          // 0..32767
    int t = tptr[0];
    float mu = mu_sched[t], sg = sigma_sched[t];
    const float LOG2E = 1.4426950408889634f;
    float inv2s2 = 1.0f / (2.0f * sg * sg);
    float s1     = 2.0f * mu * inv2s2 * LOG2E;
    float bscale = -mu * mu * inv2s2 * LOG2E;

    int n = p >> 10, rem = p & 1023, i = rem >> 5, j = rem & 31;
    const float* img = images + (size_t)n * (NC * HWDIM * HWDIM);

    float v[27];
    float pnorm = 0.f;
    #pragma unroll
    for (int c = 0; c < 3; c++)
      #pragma unroll
      for (int di = 0; di < 3; di++)
        #pragma unroll
        for (int dj = 0; dj < 3; dj++) {
            int ii = i + di - 1, jj = j + dj - 1;
            float val = 0.f;
            if (ii >= 0 && ii < HWDIM && jj >= 0 && jj < HWDIM)
                val = img[c * 1024 + ii * 32 + jj];
            v[c * 9 + di * 3 + dj] = val;
            pnorm = fmaf(val, val, pnorm);
        }

    float* kp = keys + (size_t)p * KSTR;
    #pragma unroll
    for (int u = 0; u < 27; u++) kp[u] = v[u] * s1;
    kp[27] = pnorm * bscale;
    kp[28] = v[4];    // c=0 center (k index c*9+4)
    kp[29] = v[13];   // c=1 center
    kp[30] = v[22];   // c=2 center
    kp[31] = 0.f;
}

// Kernel 2: one lane = one query; keys are wave-uniform -> scalar loads.
// Grid: 1024 blocks x 256 threads = 4096 waves = 64 query-groups x 64 key-splits.
__global__ __launch_bounds__(256) void score_main_k(
    const float* __restrict__ x, const float* __restrict__ keys,
    float* __restrict__ partials)
{
    int lane = threadIdx.x & 63;
    int wid  = __builtin_amdgcn_readfirstlane(threadIdx.x >> 6); // force wave-uniform
    int gw   = blockIdx.x * 4 + wid;    // 0..4095
    int qg   = gw & 63;                 // query group
    int split = gw >> 6;                // key split 0..63
    int q    = qg * 64 + lane;          // 0..4095

    int b = q >> 10, rem = q & 1023, h = rem >> 5, w = rem & 31;

    // Load this lane's 27-dim x-patch (circular padding), kept in VGPRs.
    float qv[27];
    const float* xb = x + (size_t)b * (NC * HWDIM * HWDIM);
    #pragma unroll
    for (int c = 0; c < 3; c++)
      #pragma unroll
      for (int di = 0; di < 3; di++)
        #pragma unroll
        for (int dj = 0; dj < 3; dj++) {
            int hh = (h + di + 31) & 31;
            int ww = (w + dj + 31) & 31;
            qv[c * 9 + di * 3 + dj] = xb[c * 1024 + hh * 32 + ww];
        }

    float m = -1e30f, s = 0.f, wc0 = 0.f, wc1 = 0.f, wc2 = 0.f;
    int key0 = split * KPS;

    for (int kc = 0; kc < KPS; kc += CHUNK) {
        float arg[CHUNK];
        #pragma unroll
        for (int kk = 0; kk < CHUNK; kk++) {
            const float* kp = keys + (size_t)(key0 + kc + kk) * KSTR; // uniform addr -> s_load
            float acc = kp[27];
            #pragma unroll
            for (int u = 0; u < 27; u++) acc = fmaf(qv[u], kp[u], acc);
            arg[kk] = acc;   // log2-domain logit
        }
        // chunk max, single rescale
        float L = arg[0];
        #pragma unroll
        for (int kk = 1; kk < CHUNK; kk++) L = fmaxf(L, arg[kk]);
        float mnew = fmaxf(m, L);
        float scale = fexp2(m - mnew);   // ==0 on first chunk (m=-1e30), accs are 0 anyway
        s *= scale; wc0 *= scale; wc1 *= scale; wc2 *= scale;
        m = mnew;
        #pragma unroll
        for (int kk = 0; kk < CHUNK; kk++) {
            float e = fexp2(arg[kk] - m);
            const float* kp = keys + (size_t)(key0 + kc + kk) * KSTR;
            s += e;
            wc0 = fmaf(e, kp[28], wc0);
            wc1 = fmaf(e, kp[29], wc1);
            wc2 = fmaf(e, kp[30], wc2);
        }
    }

    // Store partial: layout [split][q][8] -> lanes write consecutive 32B chunks.
    float* pp = partials + ((size_t)split * Q_TOTAL + q) * 8;
    float4 p0 = make_float4(m, s, wc0, wc1);
    float4 p1 = make_float4(wc2, 0.f, 0.f, 0.f);
    *(float4*)(pp)     = p0;
    *(float4*)(pp + 4) = p1;
}

// Kernel 3: combine 64 split-partials per query, write output.
__global__ __launch_bounds__(256) void combine_k(
    const float* __restrict__ x, const float* __restrict__ partials,
    const float* __restrict__ mu_sched, const float* __restrict__ sigma_sched,
    const int* __restrict__ tptr, float* __restrict__ out)
{
    int q = blockIdx.x * 256 + threadIdx.x;   // 0..4095
    int t = tptr[0];
    float mu = mu_sched[t], sg = sigma_sched[t];
    float inv_s2 = 1.0f / (sg * sg);

    float M = -1e30f;
    for (int sp = 0; sp < NSPLIT; sp++)
        M = fmaxf(M, partials[((size_t)sp * Q_TOTAL + q) * 8]);

    float S = 0.f, W0 = 0.f, W1 = 0.f, W2 = 0.f;
    for (int sp = 0; sp < NSPLIT; sp++) {
        const float* pp = partials + ((size_t)sp * Q_TOTAL + q) * 8;
        float sc = fexp2(pp[0] - M);
        S  = fmaf(pp[1], sc, S);
        W0 = fmaf(pp[2], sc, W0);
        W1 = fmaf(pp[3], sc, W1);
        W2 = fmaf(pp[4], sc, W2);
    }

    float invS = 1.0f / S;
    int b = q >> 10, rem = q & 1023;
    #pragma unroll
    for (int c = 0; c < 3; c++) {
        float Wc = (c == 0) ? W0 : (c == 1 ? W1 : W2);
        float xc = x[(size_t)b * 3072 + c * 1024 + rem];
        out[(size_t)b * 3072 + c * 1024 + rem] = -(xc - mu * Wc * invS) * inv_s2;
    }
}

extern "C" void kernel_launch(void* const* d_in, const int* in_sizes, int n_in,
                              void* d_out, int out_size, void* d_ws, size_t ws_size,
                              hipStream_t stream) {
    const float* x      = (const float*)d_in[0];
    const float* images = (const float*)d_in[1];
    const float* mu_s   = (const float*)d_in[2];
    const float* sg_s   = (const float*)d_in[3];
    const int*   tptr   = (const int*)d_in[4];
    float* out = (float*)d_out;

    float* keys     = (float*)d_ws;                          // 32768*32*4 = 4 MB
    float* partials = (float*)d_ws + (size_t)P_TOTAL * KSTR; // 64*4096*8*4 = 8 MB

    build_keys_k<<<P_TOTAL / 256, 256, 0, stream>>>(images, mu_s, sg_s, tptr, keys);
    score_main_k<<<(Q_TOTAL / 64) * NSPLIT / 4, 256, 0, stream>>>(x, keys, partials);
    combine_k<<<Q_TOTAL / 256, 256, 0, stream>>>(x, partials, mu_s, sg_s, tptr, out);
}

// Round 2
// 152.974 us; speedup vs baseline: 1.9562x; 1.9562x over previous
//
#include <hip/hip_runtime.h>
#include <cstddef>

// Problem constants
#define HWDIM 32
#define NB 4
#define NC 3
#define NIMG 32
#define P_TOTAL (NIMG * HWDIM * HWDIM)   // 32768 keys
#define Q_TOTAL (NB * HWDIM * HWDIM)     // 4096 queries
#define KDIM 32                          // padded contraction dim (27 vals + bias + 4 zero)
#define NSPLIT 32                        // key splits
#define KPS (P_TOTAL / NSPLIT)           // 1024 keys per split
#define TILES (KPS / 16)                 // 64 16-key tiles per split

typedef _Float16 half8 __attribute__((ext_vector_type(8)));
typedef float floatx4 __attribute__((ext_vector_type(4)));

__device__ __forceinline__ float fexp2(float x) { return exp2f(x); }

// ---------------------------------------------------------------------------
// Kernel 1 (fused builder): keys16[P][32] f16 (scaled vals + bias in dim 27),
// ctr[P] float4 centers, q16[Q][32] f16 (patch vals + 1.0 in dim 27).
// Logit = dot(q16_row, keys16_row) in log2 domain, ready for exp2.
// ---------------------------------------------------------------------------
__global__ __launch_bounds__(256) void build_k(
    const float* __restrict__ x, const float* __restrict__ images,
    const float* __restrict__ mu_sched, const float* __restrict__ sigma_sched,
    const int* __restrict__ tptr,
    _Float16* __restrict__ keys16, floatx4* __restrict__ ctr,
    _Float16* __restrict__ q16)
{
    int t = tptr[0];
    float mu = mu_sched[t], sg = sigma_sched[t];
    const float LOG2E = 1.4426950408889634f;
    float inv2s2 = 1.0f / (2.0f * sg * sg);
    float s1     = 2.0f * mu * inv2s2 * LOG2E;   // key value scale
    float bscale = -mu * mu * inv2s2 * LOG2E;    // pnorm bias scale

    int gid = blockIdx.x * 256 + threadIdx.x;
    if (gid < P_TOTAL) {
        int p = gid;
        int n = p >> 10, rem = p & 1023, i = rem >> 5, j = rem & 31;
        const float* img = images + (size_t)n * 3072;
        float v[27]; float pnorm = 0.f;
        #pragma unroll
        for (int c = 0; c < 3; c++)
          #pragma unroll
          for (int di = 0; di < 3; di++)
            #pragma unroll
            for (int dj = 0; dj < 3; dj++) {
                int ii = i + di - 1, jj = j + dj - 1;
                float val = 0.f;
                if (ii >= 0 && ii < 32 && jj >= 0 && jj < 32)
                    val = img[c * 1024 + ii * 32 + jj];
                v[c * 9 + di * 3 + dj] = val;
                pnorm = fmaf(val, val, pnorm);
            }
        _Float16* kp = keys16 + (size_t)p * KDIM;
        #pragma unroll
        for (int u = 0; u < 27; u++) kp[u] = (_Float16)(v[u] * s1);
        kp[27] = (_Float16)(pnorm * bscale);
        kp[28] = (_Float16)0.f; kp[29] = (_Float16)0.f;
        kp[30] = (_Float16)0.f; kp[31] = (_Float16)0.f;
        floatx4 cc = {v[4], v[13], v[22], 0.f};
        ctr[p] = cc;
    } else {
        int q = gid - P_TOTAL;   // 0..4095
        int b = q >> 10, rem = q & 1023, h = rem >> 5, w = rem & 31;
        const float* xb = x + (size_t)b * 3072;
        _Float16* qp = q16 + (size_t)q * KDIM;
        #pragma unroll
        for (int c = 0; c < 3; c++)
          #pragma unroll
          for (int di = 0; di < 3; di++)
            #pragma unroll
            for (int dj = 0; dj < 3; dj++)
                qp[c * 9 + di * 3 + dj] =
                    (_Float16)xb[c * 1024 + ((h + di + 31) & 31) * 32 + ((w + dj + 31) & 31)];
        qp[27] = (_Float16)1.0f;
        qp[28] = (_Float16)0.f; qp[29] = (_Float16)0.f;
        qp[30] = (_Float16)0.f; qp[31] = (_Float16)0.f;
    }
}

// ---------------------------------------------------------------------------
// Kernel 2: MFMA scorer. One wave = 16 queries x one 1024-key split.
// mfma_f32_16x16x32_f16: A[m=lane&15][k=quad*8+j], B[k=quad*8+j][n=lane&15],
// C/D: col(n)=lane&15, row(m)=quad*4+reg  [both HW-verified layouts].
// Loop 1: row max.  Loop 2: exp2 + weighted accumulate.  Butterfly over
// lane bits 0-3 merges the 16 column-owners of each row.
// ---------------------------------------------------------------------------
__global__ __launch_bounds__(256) void score_k(
    const _Float16* __restrict__ q16, const _Float16* __restrict__ keys16,
    const floatx4* __restrict__ ctr, float* __restrict__ partials)
{
    int lane = threadIdx.x & 63;
    int wid  = blockIdx.x * 4 + (threadIdx.x >> 6);  // 0..8191
    int qg    = wid & 255;    // query group (16 queries)
    int split = wid >> 8;     // 0..31

    int col  = lane & 15;
    int quad = lane >> 4;

    // A fragment: 8 contiguous f16 of query row (qg*16 + col)
    half8 afrag = *(const half8*)(q16 + (size_t)(qg * 16 + col) * KDIM + quad * 8);

    const _Float16* kbase = keys16 + (size_t)split * KPS * KDIM + (size_t)col * KDIM + quad * 8;
    const floatx4*  cbase = ctr + (size_t)split * KPS + col;

    // ---- Loop 1: per-row max over this split ----
    float m0 = -1e30f, m1 = -1e30f, m2 = -1e30f, m3 = -1e30f;
    {
        const _Float16* bp = kbase;
        #pragma unroll 4
        for (int tile = 0; tile < TILES; tile++) {
            half8 bfrag = *(const half8*)bp;
            floatx4 acc = {0.f, 0.f, 0.f, 0.f};
            acc = __builtin_amdgcn_mfma_f32_16x16x32_f16(afrag, bfrag, acc, 0, 0, 0);
            m0 = fmaxf(m0, acc[0]); m1 = fmaxf(m1, acc[1]);
            m2 = fmaxf(m2, acc[2]); m3 = fmaxf(m3, acc[3]);
            bp += 16 * KDIM;
        }
    }
    // merge max across the 16 lanes (cols) sharing each row
    #pragma unroll
    for (int sh = 1; sh < 16; sh <<= 1) {
        m0 = fmaxf(m0, __shfl_xor(m0, sh, 64));
        m1 = fmaxf(m1, __shfl_xor(m1, sh, 64));
        m2 = fmaxf(m2, __shfl_xor(m2, sh, 64));
        m3 = fmaxf(m3, __shfl_xor(m3, sh, 64));
    }

    // ---- Loop 2: exp2 + accumulate sum_w and weighted centers ----
    float s0 = 0.f, s1 = 0.f, s2 = 0.f, s3 = 0.f;
    float w00 = 0.f, w01 = 0.f, w02 = 0.f;
    float w10 = 0.f, w11 = 0.f, w12 = 0.f;
    float w20 = 0.f, w21 = 0.f, w22 = 0.f;
    float w30 = 0.f, w31 = 0.f, w32 = 0.f;
    {
        const _Float16* bp = kbase;
        const floatx4*  cp = cbase;
        #pragma unroll 4
        for (int tile = 0; tile < TILES; tile++) {
            half8 bfrag = *(const half8*)bp;
            floatx4 acc = {0.f, 0.f, 0.f, 0.f};
            acc = __builtin_amdgcn_mfma_f32_16x16x32_f16(afrag, bfrag, acc, 0, 0, 0);
            floatx4 c = *cp;
            float e0 = fexp2(acc[0] - m0);
            float e1 = fexp2(acc[1] - m1);
            float e2 = fexp2(acc[2] - m2);
            float e3 = fexp2(acc[3] - m3);
            s0 += e0; s1 += e1; s2 += e2; s3 += e3;
            w00 = fmaf(e0, c[0], w00); w01 = fmaf(e0, c[1], w01); w02 = fmaf(e0, c[2], w02);
            w10 = fmaf(e1, c[0], w10); w11 = fmaf(e1, c[1], w11); w12 = fmaf(e1, c[2], w12);
            w20 = fmaf(e2, c[0], w20); w21 = fmaf(e2, c[1], w21); w22 = fmaf(e2, c[2], w22);
            w30 = fmaf(e3, c[0], w30); w31 = fmaf(e3, c[1], w31); w32 = fmaf(e3, c[2], w32);
            bp += 16 * KDIM;
            cp += 16;
        }
    }
    // butterfly-sum across the 16 column-owner lanes of each row
    #pragma unroll
    for (int sh = 1; sh < 16; sh <<= 1) {
        s0 += __shfl_xor(s0, sh, 64);  s1 += __shfl_xor(s1, sh, 64);
        s2 += __shfl_xor(s2, sh, 64);  s3 += __shfl_xor(s3, sh, 64);
        w00 += __shfl_xor(w00, sh, 64); w01 += __shfl_xor(w01, sh, 64); w02 += __shfl_xor(w02, sh, 64);
        w10 += __shfl_xor(w10, sh, 64); w11 += __shfl_xor(w11, sh, 64); w12 += __shfl_xor(w12, sh, 64);
        w20 += __shfl_xor(w20, sh, 64); w21 += __shfl_xor(w21, sh, 64); w22 += __shfl_xor(w22, sh, 64);
        w30 += __shfl_xor(w30, sh, 64); w31 += __shfl_xor(w31, sh, 64); w32 += __shfl_xor(w32, sh, 64);
    }

    if (col == 0) {
        // this lane writes rows quad*4 .. quad*4+3
        float mm[4] = {m0, m1, m2, m3};
        float ss[4] = {s0, s1, s2, s3};
        float wa[4] = {w00, w10, w20, w30};
        float wb[4] = {w01, w11, w21, w31};
        float wcv[4] = {w02, w12, w22, w32};
        #pragma unroll
        for (int r = 0; r < 4; r++) {
            int q = qg * 16 + quad * 4 + r;
            float* pp = partials + ((size_t)split * Q_TOTAL + q) * 8;
            float4 p0 = make_float4(mm[r], ss[r], wa[r], wb[r]);
            *(float4*)pp = p0;
            pp[4] = wcv[r];
        }
    }
}

// ---------------------------------------------------------------------------
// Kernel 3: merge NSPLIT partials per query, write output.
// ---------------------------------------------------------------------------
__global__ __launch_bounds__(256) void combine_k(
    const float* __restrict__ x, const float* __restrict__ partials,
    const float* __restrict__ mu_sched, const float* __restrict__ sigma_sched,
    const int* __restrict__ tptr, float* __restrict__ out)
{
    int q = blockIdx.x * 256 + threadIdx.x;   // 0..4095
    int t = tptr[0];
    float mu = mu_sched[t], sg = sigma_sched[t];
    float inv_s2 = 1.0f / (sg * sg);

    float M = -1e30f;
    for (int sp = 0; sp < NSPLIT; sp++)
        M = fmaxf(M, partials[((size_t)sp * Q_TOTAL + q) * 8]);

    float S = 0.f, W0 = 0.f, W1 = 0.f, W2 = 0.f;
    for (int sp = 0; sp < NSPLIT; sp++) {
        const float* pp = partials + ((size_t)sp * Q_TOTAL + q) * 8;
        float sc = fexp2(pp[0] - M);
        S  = fmaf(pp[1], sc, S);
        W0 = fmaf(pp[2], sc, W0);
        W1 = fmaf(pp[3], sc, W1);
        W2 = fmaf(pp[4], sc, W2);
    }

    float invS = 1.0f / S;
    int b = q >> 10, rem = q & 1023;
    #pragma unroll
    for (int c = 0; c < 3; c++) {
        float Wc = (c == 0) ? W0 : (c == 1 ? W1 : W2);
        float xc = x[(size_t)b * 3072 + c * 1024 + rem];
        out[(size_t)b * 3072 + c * 1024 + rem] = -(xc - mu * Wc * invS) * inv_s2;
    }
}

extern "C" void kernel_launch(void* const* d_in, const int* in_sizes, int n_in,
                              void* d_out, int out_size, void* d_ws, size_t ws_size,
                              hipStream_t stream) {
    const float* x      = (const float*)d_in[0];
    const float* images = (const float*)d_in[1];
    const float* mu_s   = (const float*)d_in[2];
    const float* sg_s   = (const float*)d_in[3];
    const int*   tptr   = (const int*)d_in[4];
    float* out = (float*)d_out;

    // workspace layout (16B aligned throughout)
    char* ws = (char*)d_ws;
    floatx4*  ctr      = (floatx4*)ws;                                  // 512 KB
    float*    partials = (float*)(ws + (size_t)P_TOTAL * 16);           // 4 MB
    _Float16* keys16   = (_Float16*)(ws + (size_t)P_TOTAL * 16
                                        + (size_t)NSPLIT * Q_TOTAL * 8 * 4); // 2 MB
    _Float16* q16      = (_Float16*)((char*)keys16 + (size_t)P_TOTAL * KDIM * 2); // 256 KB

    build_k<<<(P_TOTAL + Q_TOTAL) / 256, 256, 0, stream>>>(
        x, images, mu_s, sg_s, tptr, keys16, ctr, q16);
    score_k<<<(Q_TOTAL / 16) * NSPLIT / 4, 256, 0, stream>>>(
        q16, keys16, ctr, partials);
    combine_k<<<Q_TOTAL / 256, 256, 0, stream>>>(
        x, partials, mu_s, sg_s, tptr, out);
}

// Round 3
// 140.657 us; speedup vs baseline: 2.1274x; 1.0876x over previous
//
#include <hip/hip_runtime.h>
#include <cstddef>

// Problem constants
#define HWDIM 32
#define NB 4
#define P_TOTAL 32768            // keys (32 images x 32 x 32)
#define Q_TOTAL 4096             // queries (4 x 32 x 32)
#define KROWB 80                 // key row bytes: 32 f16 (27 vals+bias+4 pad) + float4 ctr
#define NSPLIT 64                // key splits
#define KPS 512                  // keys per split
#define TILES 32                 // 16-key MFMA tiles per split

typedef _Float16 half8 __attribute__((ext_vector_type(8)));
typedef float floatx4 __attribute__((ext_vector_type(4)));

__device__ __forceinline__ float fexp2(float x) {
#if defined(__has_builtin) && __has_builtin(__builtin_amdgcn_exp2f)
    return __builtin_amdgcn_exp2f(x);
#else
    return exp2f(x);
#endif
}

// ---------------------------------------------------------------------------
// Builder: keys rows (80 B: f16 scaled vals + bias, float4 centers) + q16.
// Logit = dot27(q, k_scaled) + bias, in log2 domain (query dim 27 = 1.0).
// ---------------------------------------------------------------------------
__global__ __launch_bounds__(256) void build_k(
    const float* __restrict__ x, const float* __restrict__ images,
    const float* __restrict__ mu_sched, const float* __restrict__ sigma_sched,
    const int* __restrict__ tptr,
    char* __restrict__ keysg, _Float16* __restrict__ q16)
{
    int t = tptr[0];
    float mu = mu_sched[t], sg = sigma_sched[t];
    const float LOG2E = 1.4426950408889634f;
    float inv2s2 = 1.0f / (2.0f * sg * sg);
    float s1     = 2.0f * mu * inv2s2 * LOG2E;
    float bscale = -mu * mu * inv2s2 * LOG2E;

    int gid = blockIdx.x * 256 + threadIdx.x;
    if (gid < P_TOTAL) {
        int p = gid;
        int n = p >> 10, rem = p & 1023, i = rem >> 5, j = rem & 31;
        const float* img = images + (size_t)n * 3072;
        float v[27]; float pnorm = 0.f;
        #pragma unroll
        for (int c = 0; c < 3; c++)
          #pragma unroll
          for (int di = 0; di < 3; di++)
            #pragma unroll
            for (int dj = 0; dj < 3; dj++) {
                int ii = i + di - 1, jj = j + dj - 1;
                float val = 0.f;
                if (ii >= 0 && ii < 32 && jj >= 0 && jj < 32)
                    val = img[c * 1024 + ii * 32 + jj];
                v[c * 9 + di * 3 + dj] = val;
                pnorm = fmaf(val, val, pnorm);
            }
        _Float16 row[32];
        #pragma unroll
        for (int u = 0; u < 27; u++) row[u] = (_Float16)(v[u] * s1);
        row[27] = (_Float16)(pnorm * bscale);
        row[28] = (_Float16)0.f; row[29] = (_Float16)0.f;
        row[30] = (_Float16)0.f; row[31] = (_Float16)0.f;
        char* kp = keysg + (size_t)p * KROWB;
        #pragma unroll
        for (int u = 0; u < 4; u++) ((float4*)kp)[u] = ((float4*)row)[u];
        float4 cc = make_float4(v[4], v[13], v[22], 0.f);
        *(float4*)(kp + 64) = cc;
    } else if (gid < P_TOTAL + Q_TOTAL) {
        int q = gid - P_TOTAL;
        int b = q >> 10, rem = q & 1023, h = rem >> 5, w = rem & 31;
        const float* xb = x + (size_t)b * 3072;
        _Float16 row[32];
        #pragma unroll
        for (int c = 0; c < 3; c++)
          #pragma unroll
          for (int di = 0; di < 3; di++)
            #pragma unroll
            for (int dj = 0; dj < 3; dj++)
                row[c * 9 + di * 3 + dj] =
                    (_Float16)xb[c * 1024 + ((h + di + 31) & 31) * 32 + ((w + dj + 31) & 31)];
        row[27] = (_Float16)1.0f;
        row[28] = (_Float16)0.f; row[29] = (_Float16)0.f;
        row[30] = (_Float16)0.f; row[31] = (_Float16)0.f;
        _Float16* qp = q16 + (size_t)q * 32;
        #pragma unroll
        for (int u = 0; u < 4; u++) ((float4*)qp)[u] = ((float4*)row)[u];
    }
}

// ---------------------------------------------------------------------------
// Scorer: wg = 4 waves sharing one 512-key split staged in LDS (40 KB).
// Each wave: 64 queries (4 A-frags). Pass 1: max. Pass 2: exp2 (max folded
// into MFMA C-operand) + weighted-center accumulate. Butterfly over col
// lanes, col==0 writes per-split partials.
// ---------------------------------------------------------------------------
__global__ __launch_bounds__(256) void score_k(
    const _Float16* __restrict__ q16, const char* __restrict__ keysg,
    float* __restrict__ partials)
{
    __shared__ char lds[KPS * KROWB];   // 40960 B
    int tid = threadIdx.x;
    int split = blockIdx.x >> 4;        // 0..63
    int qg    = blockIdx.x & 15;        // 0..15

    // stage split keys: 2560 float4, 256 threads x 10
    {
        const float4* src = (const float4*)(keysg + (size_t)split * KPS * KROWB);
        float4* dst = (float4*)lds;
        #pragma unroll
        for (int i = 0; i < 10; i++) dst[tid + i * 256] = src[tid + i * 256];
    }
    __syncthreads();

    int lane = tid & 63;
    int wid  = tid >> 6;
    int col  = lane & 15;
    int quad = lane >> 4;
    int qbase = qg * 256 + wid * 64;

    half8 af[4];
    #pragma unroll
    for (int f = 0; f < 4; f++)
        af[f] = *(const half8*)(q16 + (size_t)(qbase + f * 16 + col) * 32 + quad * 8);

    const char* krow = lds + (size_t)col * KROWB + quad * 16;

    // ---- Pass 1: per-row max ----
    floatx4 mv[4];
    #pragma unroll
    for (int f = 0; f < 4; f++) mv[f] = (floatx4){-1e30f, -1e30f, -1e30f, -1e30f};
    {
        #pragma unroll 4
        for (int tile = 0; tile < TILES; tile++) {
            half8 b = *(const half8*)(krow + (size_t)tile * 16 * KROWB);
            #pragma unroll
            for (int f = 0; f < 4; f++) {
                floatx4 a = __builtin_amdgcn_mfma_f32_16x16x32_f16(
                    af[f], b, (floatx4){0.f, 0.f, 0.f, 0.f}, 0, 0, 0);
                #pragma unroll
                for (int r = 0; r < 4; r++) mv[f][r] = fmaxf(mv[f][r], a[r]);
            }
        }
    }
    #pragma unroll
    for (int sh = 1; sh < 16; sh <<= 1)
        #pragma unroll
        for (int f = 0; f < 4; f++)
            #pragma unroll
            for (int r = 0; r < 4; r++)
                mv[f][r] = fmaxf(mv[f][r], __shfl_xor(mv[f][r], sh, 64));

    floatx4 nm[4];
    #pragma unroll
    for (int f = 0; f < 4; f++) nm[f] = -mv[f];

    // ---- Pass 2: exp2 + accumulate ----
    floatx4 sv[4], w0[4], w1[4], w2[4];
    #pragma unroll
    for (int f = 0; f < 4; f++) {
        sv[f] = (floatx4){0.f, 0.f, 0.f, 0.f};
        w0[f] = sv[f]; w1[f] = sv[f]; w2[f] = sv[f];
    }
    {
        #pragma unroll 2
        for (int tile = 0; tile < TILES; tile++) {
            const char* kr = krow + (size_t)tile * 16 * KROWB;
            half8 b = *(const half8*)kr;
            float4 c = *(const float4*)(lds + (size_t)(tile * 16 + col) * KROWB + 64);
            #pragma unroll
            for (int f = 0; f < 4; f++) {
                floatx4 a = __builtin_amdgcn_mfma_f32_16x16x32_f16(af[f], b, nm[f], 0, 0, 0);
                #pragma unroll
                for (int r = 0; r < 4; r++) {
                    float e = fexp2(a[r]);
                    sv[f][r] += e;
                    w0[f][r] = fmaf(e, c.x, w0[f][r]);
                    w1[f][r] = fmaf(e, c.y, w1[f][r]);
                    w2[f][r] = fmaf(e, c.z, w2[f][r]);
                }
            }
        }
    }
    // butterfly-sum across the 16 col lanes
    #pragma unroll
    for (int sh = 1; sh < 16; sh <<= 1)
        #pragma unroll
        for (int f = 0; f < 4; f++)
            #pragma unroll
            for (int r = 0; r < 4; r++) {
                sv[f][r] += __shfl_xor(sv[f][r], sh, 64);
                w0[f][r] += __shfl_xor(w0[f][r], sh, 64);
                w1[f][r] += __shfl_xor(w1[f][r], sh, 64);
                w2[f][r] += __shfl_xor(w2[f][r], sh, 64);
            }

    if (col == 0) {
        #pragma unroll
        for (int f = 0; f < 4; f++)
            #pragma unroll
            for (int r = 0; r < 4; r++) {
                int q = qbase + f * 16 + quad * 4 + r;
                float* pp = partials + ((size_t)split * Q_TOTAL + q) * 8;
                *(float4*)pp = make_float4(mv[f][r], sv[f][r], w0[f][r], w1[f][r]);
                pp[4] = w2[f][r];
            }
    }
}

// ---------------------------------------------------------------------------
// Combine: merge NSPLIT partials per query, write output.
// ---------------------------------------------------------------------------
__global__ __launch_bounds__(256) void combine_k(
    const float* __restrict__ x, const float* __restrict__ partials,
    const float* __restrict__ mu_sched, const float* __restrict__ sigma_sched,
    const int* __restrict__ tptr, float* __restrict__ out)
{
    int q = blockIdx.x * 256 + threadIdx.x;   // 0..4095
    int t = tptr[0];
    float mu = mu_sched[t], sg = sigma_sched[t];
    float inv_s2 = 1.0f / (sg * sg);

    float M = -1e30f;
    for (int sp = 0; sp < NSPLIT; sp++)
        M = fmaxf(M, partials[((size_t)sp * Q_TOTAL + q) * 8]);

    float S = 0.f, W0 = 0.f, W1 = 0.f, W2 = 0.f;
    for (int sp = 0; sp < NSPLIT; sp++) {
        const float* pp = partials + ((size_t)sp * Q_TOTAL + q) * 8;
        float sc = fexp2(pp[0] - M);
        S  = fmaf(pp[1], sc, S);
        W0 = fmaf(pp[2], sc, W0);
        W1 = fmaf(pp[3], sc, W1);
        W2 = fmaf(pp[4], sc, W2);
    }

    float invS = 1.0f / S;
    int b = q >> 10, rem = q & 1023;
    #pragma unroll
    for (int c = 0; c < 3; c++) {
        float Wc = (c == 0) ? W0 : (c == 1 ? W1 : W2);
        float xc = x[(size_t)b * 3072 + c * 1024 + rem];
        out[(size_t)b * 3072 + c * 1024 + rem] = -(xc - mu * Wc * invS) * inv_s2;
    }
}

extern "C" void kernel_launch(void* const* d_in, const int* in_sizes, int n_in,
                              void* d_out, int out_size, void* d_ws, size_t ws_size,
                              hipStream_t stream) {
    const float* x      = (const float*)d_in[0];
    const float* images = (const float*)d_in[1];
    const float* mu_s   = (const float*)d_in[2];
    const float* sg_s   = (const float*)d_in[3];
    const int*   tptr   = (const int*)d_in[4];
    float* out = (float*)d_out;

    // workspace layout
    float*    partials = (float*)d_ws;                                   // 8 MB
    char*     keysg    = (char*)d_ws + (size_t)NSPLIT * Q_TOTAL * 8 * 4; // 2.62 MB
    _Float16* q16      = (_Float16*)(keysg + (size_t)P_TOTAL * KROWB);   // 256 KB

    build_k<<<(P_TOTAL + Q_TOTAL) / 256, 256, 0, stream>>>(
        x, images, mu_s, sg_s, tptr, keysg, q16);
    score_k<<<16 * NSPLIT, 256, 0, stream>>>(q16, keysg, partials);
    combine_k<<<Q_TOTAL / 256, 256, 0, stream>>>(
        x, partials, mu_s, sg_s, tptr, out);
}